// Round 5
// baseline (845.338 us; speedup 1.0000x reference)
//
#include <hip/hip_runtime.h>
#include <stdint.h>

#define HIST 336
#define CNTX 168
#define PRED 24
#define HID 128
#define NFEAT 5
#define EMB 50
#define NLAGS 168
#define IN_DIM 218
#define NSAMP 8192
#define G3 384

// workspace layout (float offsets)
#define WS_XS     0         // 336
#define WS_SC     336       // 1
#define WS_TF     340       // 168*50
#define WS_YM     8740      // 24*50
#define WS_KEYS   9940      // 24*4 uint32 (key_n, key_g per step)
#define WS_ENCGI  10036     // 168*384
#define WS_GISH   74548     // 24*384
#define WS_HLAST  83764     // 128
#define WS_WIHT   83892     // 24*384 (W_ih lag cols transposed)
// total 93108 floats = 372432 B

// ---------------- threefry2x32 core (20 rounds) ----------------
__device__ __forceinline__ uint32_t rotl32(uint32_t v, int r){ return (v<<r)|(v>>(32-r)); }

__device__ __forceinline__ void threefry(uint32_t k0, uint32_t k1, uint32_t x0, uint32_t x1,
                                         uint32_t &o0, uint32_t &o1){
  uint32_t ks2 = k0 ^ k1 ^ 0x1BD11BDAu;
  x0 += k0; x1 += k1;
#define TFR(a) { x0 += x1; x1 = rotl32(x1,(a)); x1 ^= x0; }
  TFR(13) TFR(15) TFR(26) TFR(6)
  x0 += k1; x1 += ks2 + 1u;
  TFR(17) TFR(29) TFR(16) TFR(24)
  x0 += ks2; x1 += k0 + 2u;
  TFR(13) TFR(15) TFR(26) TFR(6)
  x0 += k0; x1 += k1 + 3u;
  TFR(17) TFR(29) TFR(16) TFR(24)
  x0 += k1; x1 += ks2 + 4u;
  TFR(13) TFR(15) TFR(26) TFR(6)
  x0 += ks2; x1 += k0 + 5u;
#undef TFR
  o0 = x0; o1 = x1;
}

// ---------------- partitionable (foldlike) JAX PRNG semantics ----------------
// split(key, n): keys[i] = threefry(key; counter=(0, i))  -> full (o0,o1) pair
// random_bits(key, 32, (n,)): bits[i] = o0(key;0,i) ^ o1(key;0,i)
// scalar bits: counter (0,0)

__device__ __forceinline__ void tf_split2(uint32_t k0, uint32_t k1,
                                          uint32_t &a0, uint32_t &a1,
                                          uint32_t &b0, uint32_t &b1){
  threefry(k0,k1, 0u,0u, a0,a1);
  threefry(k0,k1, 0u,1u, b0,b1);
}

__device__ __forceinline__ void tf_split3(uint32_t k0, uint32_t k1,
                                          uint32_t &a0, uint32_t &a1,
                                          uint32_t &b0, uint32_t &b1,
                                          uint32_t &c0, uint32_t &c1){
  threefry(k0,k1, 0u,0u, a0,a1);
  threefry(k0,k1, 0u,1u, b0,b1);
  threefry(k0,k1, 0u,2u, c0,c1);
}

__device__ __forceinline__ uint32_t tf_bits1(uint32_t k0, uint32_t k1){
  uint32_t o0,o1; threefry(k0,k1, 0u,0u, o0,o1); return o0 ^ o1;
}

__device__ __forceinline__ uint32_t tf_bits_at(uint32_t k0, uint32_t k1, uint32_t i){
  uint32_t o0,o1; threefry(k0,k1, 0u,i, o0,o1); return o0 ^ o1;
}

__device__ __forceinline__ float bits_to_f01(uint32_t b){
  return __uint_as_float((b>>9) | 0x3f800000u) - 1.0f;
}

// XLA ErfInv32 polynomial
__device__ __forceinline__ float erfinv32(float x){
  float w = -log1pf(-x*x);
  float p;
  if (w < 5.0f){
    w = w - 2.5f;
    p = 2.81022636e-08f;
    p = fmaf(p, w, 3.43273939e-07f);
    p = fmaf(p, w, -3.5233877e-06f);
    p = fmaf(p, w, -4.39150654e-06f);
    p = fmaf(p, w, 0.00021858087f);
    p = fmaf(p, w, -0.00125372503f);
    p = fmaf(p, w, -0.00417768164f);
    p = fmaf(p, w, 0.246640727f);
    p = fmaf(p, w, 1.50140941f);
  } else {
    w = sqrtf(w) - 3.0f;
    p = -0.000200214257f;
    p = fmaf(p, w, 0.000100950558f);
    p = fmaf(p, w, 0.00134934322f);
    p = fmaf(p, w, -0.00367342844f);
    p = fmaf(p, w, 0.00573950773f);
    p = fmaf(p, w, -0.0076224613f);
    p = fmaf(p, w, 0.00943887047f);
    p = fmaf(p, w, 1.00167406f);
    p = fmaf(p, w, 2.83297682f);
  }
  return p*x;
}

// normal(key, ()) : uniform in (nextafter(-1,0), 1), sqrt(2)*erfinv
__device__ __forceinline__ float normal_from_key(uint32_t k0, uint32_t k1){
  uint32_t b = tf_bits1(k0,k1);
  const float lo = -0.99999994f;
  float f = bits_to_f01(b);
  float u = fmaxf(lo, f*2.0f + lo);   // (maxval-minval) rounds to exactly 2.0f
  return 1.41421356f * erfinv32(u);
}

// JAX _gamma_one, alpha >= 1 branch (boost==1); exact key consumption order
__device__ float gamma_sample(uint32_t k0, uint32_t k1, float alpha){
  float d = __fsub_rn(alpha, 0.33333334f);
  float c = 0.33333334f / sqrtf(d);   // == 1/sqrt(9d) up to ulp
  uint32_t ck0,ck1, sb0,sb1;
  tf_split2(k0,k1, ck0,ck1, sb0,sb1); // (key, subkey); subkey=boost key unused (alpha>=1)
  float V;
  for(;;){
    uint32_t nk0,nk1, xk0,xk1, uk0,uk1;
    tf_split3(ck0,ck1, nk0,nk1, xk0,xk1, uk0,uk1);
    ck0=nk0; ck1=nk1;
    float x, v;
    do {
      uint32_t xa0,xa1, xb0,xb1;
      tf_split2(xk0,xk1, xa0,xa1, xb0,xb1);
      xk0=xa0; xk1=xa1;
      x = normal_from_key(xb0,xb1);
      v = __fadd_rn(1.0f, __fmul_rn(x, c));
    } while (v <= 0.0f);
    float X  = __fmul_rn(x, x);
    float Vv = __fmul_rn(__fmul_rn(v, v), v);
    float U  = bits_to_f01(tf_bits1(uk0,uk1));
    float t1 = __fsub_rn(1.0f, __fmul_rn(0.0331f, __fmul_rn(X, X)));
    bool cont = (U >= t1);
    if (cont){
      float lhs = logf(U);
      float rhs = __fadd_rn(__fmul_rn(0.5f, X),
                  __fmul_rn(d, __fadd_rn(__fsub_rn(1.0f, Vv), logf(Vv))));
      cont = (lhs >= rhs);
    }
    if (!cont){ V = Vv; break; }
  }
  return d*V;
}

__device__ __forceinline__ float softplus_f(float x){
  float amax = fmaxf(x, 0.0f);
  return amax + log1pf(expf(-fabsf(x)));
}

// ---------------- K1: scale, xs, tf, ym, step keys ----------------
__global__ __launch_bounds__(256) void k1_prep(const float* __restrict__ x,
                                               const float* __restrict__ xmark,
                                               const float* __restrict__ ymark,
                                               const float* __restrict__ Wemb,
                                               const float* __restrict__ bemb,
                                               float* __restrict__ ws){
  __shared__ float red[256];
  __shared__ float s_sc;
  int t = threadIdx.x;
  float a = 0.f;
  if (t < CNTX) a = fabsf(x[CNTX + t]);
  red[t] = a;
  __syncthreads();
  for(int s=128; s>0; s>>=1){ if(t<s) red[t]+=red[t+s]; __syncthreads(); }
  if (t==0){ s_sc = fmaxf(red[0]/168.0f, 1e-5f); ws[WS_SC]=s_sc; }
  __syncthreads();
  float sc = s_sc;
  for(int i=t; i<HIST; i+=256) ws[WS_XS+i] = x[i]/sc;
  for(int idx=t; idx<CNTX*EMB; idx+=256){
    int tt = idx/EMB, e = idx%EMB;
    float acc = bemb[e];
    for(int f=0; f<NFEAT; f++) acc += xmark[(CNTX+tt)*NFEAT+f]*Wemb[f*EMB+e];
    ws[WS_TF+idx] = acc;
  }
  for(int idx=t; idx<PRED*EMB; idx+=256){
    int kk = idx/EMB, e = idx%EMB;
    float acc = bemb[e];
    for(int f=0; f<NFEAT; f++) acc += ymark[kk*NFEAT+f]*Wemb[f*EMB+e];
    ws[WS_YM+idx] = acc;
  }
  if (t==0){
    uint32_t* kp = reinterpret_cast<uint32_t*>(ws + WS_KEYS);
    uint32_t c0 = 0u, c1 = 42u;  // jax.random.key(42)
    for(int k=0;k<PRED;k++){
      uint32_t a0,a1,b0,b1;
      tf_split2(c0,c1, a0,a1, b0,b1);   // keys[0]=carry key, keys[1]=sk
      c0=a0; c1=a1;
      uint32_t n0,n1,g0,g1;
      tf_split2(b0,b1, n0,n1, g0,g1);   // key_n, key_g
      kp[k*4+0]=n0; kp[k*4+1]=n1; kp[k*4+2]=g0; kp[k*4+3]=g1;
    }
  }
}

// ---------------- K2: enc_gi (t<168) and gi_shared (t>=168) ----------------
__global__ __launch_bounds__(256) void k2_gi(const float* __restrict__ Wih,
                                             const float* __restrict__ bih,
                                             const float* __restrict__ bhh,
                                             float* __restrict__ ws){
  int idx = blockIdx.x*256 + threadIdx.x;
  if (idx >= 192*G3) return;
  int t = idx / G3, r = idx % G3;
  const float* wr = Wih + r*IN_DIM;
  const float* xs = ws + WS_XS;
  float acc = bih[r] + (r < 256 ? bhh[r] : 0.0f);
  if (t < CNTX){
    const float* tf = ws + WS_TF + t*EMB;
    for(int j=0;j<NLAGS;j++) acc += wr[j]*xs[CNTX + t - 1 - j];
    for(int e=0;e<EMB;e++)   acc += wr[NLAGS+e]*tf[e];
    ws[WS_ENCGI + t*G3 + r] = acc;
  } else {
    int k = t - CNTX;
    const float* ym = ws + WS_YM + k*EMB;
    for(int e=0;e<EMB;e++)   acc += wr[NLAGS+e]*ym[e];
    for(int i=k;i<NLAGS;i++) acc += wr[i]*xs[HIST-1-i+k];
    ws[WS_GISH + k*G3 + r] = acc;
  }
}

// ---------------- K2b: transpose W_ih lag cols 0..23 ----------------
__global__ __launch_bounds__(256) void k2b_wiht(const float* __restrict__ Wih,
                                                float* __restrict__ ws){
  int idx = blockIdx.x*256 + threadIdx.x;
  if (idx >= PRED*G3) return;
  int r = idx / PRED, i = idx % PRED;
  ws[WS_WIHT + i*G3 + r] = Wih[r*IN_DIM + i];
}

// ---------------- K3: encoder GRU, 1 block, 384 threads, W row in regs ----------------
__global__ __launch_bounds__(384) void k3_enc(const float* __restrict__ Whh,
                                              const float* __restrict__ bhh,
                                              float* __restrict__ ws){
  __shared__ __align__(16) float h[HID];
  __shared__ float grz[256];
  __shared__ float hnv[HID];
  int r = threadIdx.x;
  float4 w[32];
  const float4* wr = (const float4*)(Whh + r*HID);
  #pragma unroll
  for(int i=0;i<32;i++) w[i] = wr[i];
  float bh = (r>=256)? bhh[r] : 0.0f;
  if (r < HID) h[r] = 0.0f;
  __syncthreads();
  const float* encgi = ws + WS_ENCGI;
  for(int t=0;t<CNTX;t++){
    float acc = 0.f;
    #pragma unroll
    for(int i=0;i<32;i++){
      float4 hv = *(const float4*)&h[4*i];
      float4 ww = w[i];
      acc = fmaf(ww.x,hv.x, fmaf(ww.y,hv.y, fmaf(ww.z,hv.z, fmaf(ww.w,hv.w, acc))));
    }
    if (r < 256) grz[r] = encgi[t*G3+r] + acc;
    else         hnv[r-256] = acc + bh;
    __syncthreads();
    if (r < HID){
      float rr = 1.0f/(1.0f+expf(-grz[r]));
      float zz = 1.0f/(1.0f+expf(-grz[128+r]));
      float inv = encgi[t*G3+256+r];
      float nn = tanhf(inv + rr*hnv[r]);
      h[r] = (1.0f-zz)*nn + zz*h[r];
    }
    __syncthreads();
  }
  if (r < HID) ws[WS_HLAST + r] = h[r];
}

// ---------------- K4: decoder, 256 blocks x 512 thr, 32 samples/block ----------------
#define SPB 32
#define THR 512
#define HROW 132   // padded h row (bank spread for projection)

__global__ __launch_bounds__(512) void k4_dec(const float* __restrict__ Whh,
                                              const float* __restrict__ bhh,
                                              const float* __restrict__ Wproj,
                                              const float* __restrict__ bproj,
                                              const float* __restrict__ ws,
                                              float* __restrict__ out){
  __shared__ __align__(16) float h[SPB][HROW];     // 16.9 KB
  __shared__ float wT[16*G3];                      // 24 KB (transposed W tile)
  __shared__ float shist[SPB][PRED];               // 3 KB (samp/sc history)
  __shared__ float parr[SPB][4];
  __shared__ float wp[HID*3];
  __shared__ float bp[3];
  __shared__ uint32_t skeys[PRED*4];

  int t = threadIdx.x;
  int b = blockIdx.x;
  int lane = t & 63;
  int sp = t >> 6;              // wave id = sample group (4 samples)
  int j0 = lane, j1 = lane + 64;
  int s_base = sp*4;

  float sc = ws[WS_SC];
  const float* gish = ws + WS_GISH;
  const float* wihT = ws + WS_WIHT;

  for(int idx=t; idx<HID*3; idx+=THR) wp[idx] = Wproj[idx];
  if (t < 3) bp[t] = bproj[t];
  if (t < PRED*4) skeys[t] = reinterpret_cast<const uint32_t*>(ws + WS_KEYS)[t];
  {
    float h0 = ws[WS_HLAST + j0], h1 = ws[WS_HLAST + j1];
    #pragma unroll
    for(int ss=0;ss<4;ss++){ h[s_base+ss][j0] = h0; h[s_base+ss][j1] = h1; }
  }
  float bhn0 = bhh[256+j0], bhn1 = bhh[256+j1];
  __syncthreads();

  #pragma unroll 1
  for(int k=0;k<PRED;k++){
    float aR[4][2], aZ[4][2], aHN[4][2], aIN[4][2];
    float g_r0 = gish[k*G3 + j0],      g_r1 = gish[k*G3 + j1];
    float g_z0 = gish[k*G3 + 128+j0],  g_z1 = gish[k*G3 + 128+j1];
    float g_n0 = gish[k*G3 + 256+j0],  g_n1 = gish[k*G3 + 256+j1];
    #pragma unroll
    for(int ss=0;ss<4;ss++){
      aR[ss][0]=g_r0;  aR[ss][1]=g_r1;
      aZ[ss][0]=g_z0;  aZ[ss][1]=g_z1;
      aIN[ss][0]=g_n0; aIN[ss][1]=g_n1;
      aHN[ss][0]=bhn0; aHN[ss][1]=bhn1;
    }
    // recent generated-sample lag contributions (i < k)
    #pragma unroll 1
    for(int i=0;i<k;i++){
      const float* wrow = wihT + i*G3;
      float w_r0 = wrow[j0],     w_r1 = wrow[j1];
      float w_z0 = wrow[128+j0], w_z1 = wrow[128+j1];
      float w_n0 = wrow[256+j0], w_n1 = wrow[256+j1];
      #pragma unroll
      for(int ss=0;ss<4;ss++){
        float sh = shist[s_base+ss][k-1-i];
        aR[ss][0]  = fmaf(w_r0, sh, aR[ss][0]);  aR[ss][1]  = fmaf(w_r1, sh, aR[ss][1]);
        aZ[ss][0]  = fmaf(w_z0, sh, aZ[ss][0]);  aZ[ss][1]  = fmaf(w_z1, sh, aZ[ss][1]);
        aIN[ss][0] = fmaf(w_n0, sh, aIN[ss][0]); aIN[ss][1] = fmaf(w_n1, sh, aIN[ss][1]);
      }
    }
    // main h-matvec: 8 K-tiles of 16, W staged transposed in LDS
    #pragma unroll 1
    for(int kt=0; kt<8; kt++){
      __syncthreads();
      #pragma unroll
      for(int i=0;i<3;i++){
        int f4 = t + i*THR;               // 0..1535 float4s
        int rr = f4 >> 2, c4 = f4 & 3;
        float4 g = *(const float4*)&Whh[rr*HID + kt*16 + c4*4];
        wT[(c4*4+0)*G3 + rr] = g.x;
        wT[(c4*4+1)*G3 + rr] = g.y;
        wT[(c4*4+2)*G3 + rr] = g.z;
        wT[(c4*4+3)*G3 + rr] = g.w;
      }
      __syncthreads();
      #pragma unroll
      for(int c4=0;c4<4;c4++){
        float hx[4], hy[4], hz[4], hw[4];
        #pragma unroll
        for(int ss=0;ss<4;ss++){
          float4 hv = *(const float4*)&h[s_base+ss][kt*16+c4*4];
          hx[ss]=hv.x; hy[ss]=hv.y; hz[ss]=hv.z; hw[ss]=hv.w;
        }
        #pragma unroll
        for(int u=0;u<4;u++){
          const float* wc = &wT[(c4*4+u)*G3];
          float wr0 = wc[j0], wz0 = wc[128+j0], wn0 = wc[256+j0];
          float wr1 = wc[j1], wz1 = wc[128+j1], wn1 = wc[256+j1];
          #pragma unroll
          for(int ss=0;ss<4;ss++){
            float hc = (u==0)?hx[ss]:(u==1)?hy[ss]:(u==2)?hz[ss]:hw[ss];
            aR[ss][0]  = fmaf(wr0, hc, aR[ss][0]);  aR[ss][1]  = fmaf(wr1, hc, aR[ss][1]);
            aZ[ss][0]  = fmaf(wz0, hc, aZ[ss][0]);  aZ[ss][1]  = fmaf(wz1, hc, aZ[ss][1]);
            aHN[ss][0] = fmaf(wn0, hc, aHN[ss][0]); aHN[ss][1] = fmaf(wn1, hc, aHN[ss][1]);
          }
        }
      }
    }
    __syncthreads();   // all reads of old h done
    // gates + h update (each thread owns its (s, j0/j1) cells)
    #pragma unroll
    for(int ss=0;ss<4;ss++){
      int s = s_base+ss;
      {
        float rr = 1.0f/(1.0f+expf(-aR[ss][0]));
        float zz = 1.0f/(1.0f+expf(-aZ[ss][0]));
        float nn = tanhf(aIN[ss][0] + rr*aHN[ss][0]);
        h[s][j0] = (1.0f-zz)*nn + zz*h[s][j0];
      }
      {
        float rr = 1.0f/(1.0f+expf(-aR[ss][1]));
        float zz = 1.0f/(1.0f+expf(-aZ[ss][1]));
        float nn = tanhf(aIN[ss][1] + rr*aHN[ss][1]);
        h[s][j1] = (1.0f-zz)*nn + zz*h[s][j1];
      }
    }
    __syncthreads();
    // projection: 96 threads, p[s][c]
    if (t < SPB*3){
      int s = t/3, c2 = t%3;
      float acc = bp[c2];
      for(int l=0;l<HID;l++) acc = fmaf(h[s][l], wp[l*3+c2], acc);
      parr[s][c2] = acc;
    }
    __syncthreads();
    // sampling: 32 threads (lane s of wave 0)
    if (t < SPB){
      int s = t, gs = b*SPB + s;
      float p0 = parr[s][0], loc = parr[s][1], p2 = parr[s][2];
      float df = 2.0f + softplus_f(p0);
      float half_df = df*0.5f;
      float sigma = softplus_f(p2);
      uint32_t kn0 = skeys[k*4+0], kn1 = skeys[k*4+1];
      uint32_t kg0 = skeys[k*4+2], kg1 = skeys[k*4+3];
      // --- normal draw: partitionable random_bits: bits[i] = o0(0,i)^o1(0,i) ---
      uint32_t bnb = tf_bits_at(kn0, kn1, (uint32_t)gs);
      const float lo = -0.99999994f;
      float un = fmaxf(lo, bits_to_f01(bnb)*2.0f + lo);
      float nval = 1.41421356f * erfinv32(un);
      // --- gamma: key_g. split(key_g, 8192)[i] = threefry(key_g; 0, i) ---
      uint32_t gk0, gk1;
      threefry(kg0, kg1, 0u, (uint32_t)gs, gk0, gk1);
      float g = gamma_sample(gk0, gk1, half_df);
      float tval = nval * sqrtf(half_df / g);
      float samp = (loc + sigma*tval)*sc;
      out[gs*PRED + k] = samp;
      shist[s][k] = samp / sc;
    }
    __syncthreads();
  }
}

extern "C" void kernel_launch(void* const* d_in, const int* in_sizes, int n_in,
                              void* d_out, int out_size, void* d_ws, size_t ws_size,
                              hipStream_t stream){
  const float* x     = (const float*)d_in[0];
  const float* xmark = (const float*)d_in[1];
  const float* ymark = (const float*)d_in[2];
  const float* Wemb  = (const float*)d_in[3];
  const float* bemb  = (const float*)d_in[4];
  const float* Wih   = (const float*)d_in[5];
  const float* Whh   = (const float*)d_in[6];
  const float* bih   = (const float*)d_in[7];
  const float* bhh   = (const float*)d_in[8];
  const float* Wproj = (const float*)d_in[9];
  const float* bproj = (const float*)d_in[10];
  float* ws  = (float*)d_ws;
  float* out = (float*)d_out;

  hipLaunchKernelGGL(k1_prep, dim3(1), dim3(256), 0, stream, x, xmark, ymark, Wemb, bemb, ws);
  hipLaunchKernelGGL(k2_gi, dim3(288), dim3(256), 0, stream, Wih, bih, bhh, ws);
  hipLaunchKernelGGL(k2b_wiht, dim3((PRED*G3+255)/256), dim3(256), 0, stream, Wih, ws);
  hipLaunchKernelGGL(k3_enc, dim3(1), dim3(384), 0, stream, Whh, bhh, ws);
  hipLaunchKernelGGL(k4_dec, dim3(NSAMP/SPB), dim3(THR), 0, stream, Whh, bhh, Wproj, bproj, ws, out);
}

// Round 6
// 805.479 us; speedup vs baseline: 1.0495x; 1.0495x over previous
//
#include <hip/hip_runtime.h>
#include <stdint.h>

#define HIST 336
#define CNTX 168
#define PRED 24
#define HID 128
#define NFEAT 5
#define EMB 50
#define NLAGS 168
#define IN_DIM 218
#define NSAMP 8192
#define G3 384

// workspace layout (float offsets)
#define WS_XS     0         // 336
#define WS_SC     336       // 1
#define WS_TF     340       // 168*50
#define WS_YM     8740      // 24*50
#define WS_KEYS   9940      // 24*4 uint32 (key_n, key_g per step)
#define WS_ENCGI  10036     // 168*384
#define WS_GISH   74548     // 24*384
#define WS_HLAST  83764     // 128
#define WS_WIHT   83892     // 24*384 (W_ih lag cols transposed)

// ---------------- threefry2x32 core (20 rounds) ----------------
__device__ __forceinline__ uint32_t rotl32(uint32_t v, int r){ return (v<<r)|(v>>(32-r)); }

__device__ __forceinline__ void threefry(uint32_t k0, uint32_t k1, uint32_t x0, uint32_t x1,
                                         uint32_t &o0, uint32_t &o1){
  uint32_t ks2 = k0 ^ k1 ^ 0x1BD11BDAu;
  x0 += k0; x1 += k1;
#define TFR(a) { x0 += x1; x1 = rotl32(x1,(a)); x1 ^= x0; }
  TFR(13) TFR(15) TFR(26) TFR(6)
  x0 += k1; x1 += ks2 + 1u;
  TFR(17) TFR(29) TFR(16) TFR(24)
  x0 += ks2; x1 += k0 + 2u;
  TFR(13) TFR(15) TFR(26) TFR(6)
  x0 += k0; x1 += k1 + 3u;
  TFR(17) TFR(29) TFR(16) TFR(24)
  x0 += k1; x1 += ks2 + 4u;
  TFR(13) TFR(15) TFR(26) TFR(6)
  x0 += ks2; x1 += k0 + 5u;
#undef TFR
  o0 = x0; o1 = x1;
}

// ---------------- partitionable (foldlike) JAX PRNG semantics ----------------
__device__ __forceinline__ void tf_split2(uint32_t k0, uint32_t k1,
                                          uint32_t &a0, uint32_t &a1,
                                          uint32_t &b0, uint32_t &b1){
  threefry(k0,k1, 0u,0u, a0,a1);
  threefry(k0,k1, 0u,1u, b0,b1);
}

__device__ __forceinline__ void tf_split3(uint32_t k0, uint32_t k1,
                                          uint32_t &a0, uint32_t &a1,
                                          uint32_t &b0, uint32_t &b1,
                                          uint32_t &c0, uint32_t &c1){
  threefry(k0,k1, 0u,0u, a0,a1);
  threefry(k0,k1, 0u,1u, b0,b1);
  threefry(k0,k1, 0u,2u, c0,c1);
}

__device__ __forceinline__ uint32_t tf_bits1(uint32_t k0, uint32_t k1){
  uint32_t o0,o1; threefry(k0,k1, 0u,0u, o0,o1); return o0 ^ o1;
}

__device__ __forceinline__ uint32_t tf_bits_at(uint32_t k0, uint32_t k1, uint32_t i){
  uint32_t o0,o1; threefry(k0,k1, 0u,i, o0,o1); return o0 ^ o1;
}

__device__ __forceinline__ float bits_to_f01(uint32_t b){
  return __uint_as_float((b>>9) | 0x3f800000u) - 1.0f;
}

// XLA ErfInv32 polynomial
__device__ __forceinline__ float erfinv32(float x){
  float w = -log1pf(-x*x);
  float p;
  if (w < 5.0f){
    w = w - 2.5f;
    p = 2.81022636e-08f;
    p = fmaf(p, w, 3.43273939e-07f);
    p = fmaf(p, w, -3.5233877e-06f);
    p = fmaf(p, w, -4.39150654e-06f);
    p = fmaf(p, w, 0.00021858087f);
    p = fmaf(p, w, -0.00125372503f);
    p = fmaf(p, w, -0.00417768164f);
    p = fmaf(p, w, 0.246640727f);
    p = fmaf(p, w, 1.50140941f);
  } else {
    w = sqrtf(w) - 3.0f;
    p = -0.000200214257f;
    p = fmaf(p, w, 0.000100950558f);
    p = fmaf(p, w, 0.00134934322f);
    p = fmaf(p, w, -0.00367342844f);
    p = fmaf(p, w, 0.00573950773f);
    p = fmaf(p, w, -0.0076224613f);
    p = fmaf(p, w, 0.00943887047f);
    p = fmaf(p, w, 1.00167406f);
    p = fmaf(p, w, 2.83297682f);
  }
  return p*x;
}

__device__ __forceinline__ float normal_from_key(uint32_t k0, uint32_t k1){
  uint32_t b = tf_bits1(k0,k1);
  const float lo = -0.99999994f;
  float f = bits_to_f01(b);
  float u = fmaxf(lo, f*2.0f + lo);
  return 1.41421356f * erfinv32(u);
}

// JAX _gamma_one, alpha >= 1 branch (boost==1)
__device__ float gamma_sample(uint32_t k0, uint32_t k1, float alpha){
  float d = __fsub_rn(alpha, 0.33333334f);
  float c = 0.33333334f / sqrtf(d);
  uint32_t ck0,ck1, sb0,sb1;
  tf_split2(k0,k1, ck0,ck1, sb0,sb1);
  float V;
  for(;;){
    uint32_t nk0,nk1, xk0,xk1, uk0,uk1;
    tf_split3(ck0,ck1, nk0,nk1, xk0,xk1, uk0,uk1);
    ck0=nk0; ck1=nk1;
    float x, v;
    do {
      uint32_t xa0,xa1, xb0,xb1;
      tf_split2(xk0,xk1, xa0,xa1, xb0,xb1);
      xk0=xa0; xk1=xa1;
      x = normal_from_key(xb0,xb1);
      v = __fadd_rn(1.0f, __fmul_rn(x, c));
    } while (v <= 0.0f);
    float X  = __fmul_rn(x, x);
    float Vv = __fmul_rn(__fmul_rn(v, v), v);
    float U  = bits_to_f01(tf_bits1(uk0,uk1));
    float t1 = __fsub_rn(1.0f, __fmul_rn(0.0331f, __fmul_rn(X, X)));
    bool cont = (U >= t1);
    if (cont){
      float lhs = logf(U);
      float rhs = __fadd_rn(__fmul_rn(0.5f, X),
                  __fmul_rn(d, __fadd_rn(__fsub_rn(1.0f, Vv), logf(Vv))));
      cont = (lhs >= rhs);
    }
    if (!cont){ V = Vv; break; }
  }
  return d*V;
}

__device__ __forceinline__ float softplus_f(float x){
  float amax = fmaxf(x, 0.0f);
  return amax + log1pf(expf(-fabsf(x)));
}

// ---------------- K1: scale, xs, tf, ym, step keys ----------------
__global__ __launch_bounds__(256) void k1_prep(const float* __restrict__ x,
                                               const float* __restrict__ xmark,
                                               const float* __restrict__ ymark,
                                               const float* __restrict__ Wemb,
                                               const float* __restrict__ bemb,
                                               float* __restrict__ ws){
  __shared__ float red[256];
  __shared__ float s_sc;
  int t = threadIdx.x;
  float a = 0.f;
  if (t < CNTX) a = fabsf(x[CNTX + t]);
  red[t] = a;
  __syncthreads();
  for(int s=128; s>0; s>>=1){ if(t<s) red[t]+=red[t+s]; __syncthreads(); }
  if (t==0){ s_sc = fmaxf(red[0]/168.0f, 1e-5f); ws[WS_SC]=s_sc; }
  __syncthreads();
  float sc = s_sc;
  for(int i=t; i<HIST; i+=256) ws[WS_XS+i] = x[i]/sc;
  for(int idx=t; idx<CNTX*EMB; idx+=256){
    int tt = idx/EMB, e = idx%EMB;
    float acc = bemb[e];
    for(int f=0; f<NFEAT; f++) acc += xmark[(CNTX+tt)*NFEAT+f]*Wemb[f*EMB+e];
    ws[WS_TF+idx] = acc;
  }
  for(int idx=t; idx<PRED*EMB; idx+=256){
    int kk = idx/EMB, e = idx%EMB;
    float acc = bemb[e];
    for(int f=0; f<NFEAT; f++) acc += ymark[kk*NFEAT+f]*Wemb[f*EMB+e];
    ws[WS_YM+idx] = acc;
  }
  if (t==0){
    uint32_t* kp = reinterpret_cast<uint32_t*>(ws + WS_KEYS);
    uint32_t c0 = 0u, c1 = 42u;
    for(int k=0;k<PRED;k++){
      uint32_t a0,a1,b0,b1;
      tf_split2(c0,c1, a0,a1, b0,b1);
      c0=a0; c1=a1;
      uint32_t n0,n1,g0,g1;
      tf_split2(b0,b1, n0,n1, g0,g1);
      kp[k*4+0]=n0; kp[k*4+1]=n1; kp[k*4+2]=g0; kp[k*4+3]=g1;
    }
  }
}

// ---------------- K2: enc_gi (t<168) and gi_shared (t>=168) ----------------
__global__ __launch_bounds__(256) void k2_gi(const float* __restrict__ Wih,
                                             const float* __restrict__ bih,
                                             const float* __restrict__ bhh,
                                             float* __restrict__ ws){
  int idx = blockIdx.x*256 + threadIdx.x;
  if (idx >= 192*G3) return;
  int t = idx / G3, r = idx % G3;
  const float* wr = Wih + r*IN_DIM;
  const float* xs = ws + WS_XS;
  float acc = bih[r] + (r < 256 ? bhh[r] : 0.0f);
  if (t < CNTX){
    const float* tf = ws + WS_TF + t*EMB;
    for(int j=0;j<NLAGS;j++) acc += wr[j]*xs[CNTX + t - 1 - j];
    for(int e=0;e<EMB;e++)   acc += wr[NLAGS+e]*tf[e];
    ws[WS_ENCGI + t*G3 + r] = acc;
  } else {
    int k = t - CNTX;
    const float* ym = ws + WS_YM + k*EMB;
    for(int e=0;e<EMB;e++)   acc += wr[NLAGS+e]*ym[e];
    for(int i=k;i<NLAGS;i++) acc += wr[i]*xs[HIST-1-i+k];
    ws[WS_GISH + k*G3 + r] = acc;
  }
}

// ---------------- K2b: transpose W_ih lag cols 0..23 ----------------
__global__ __launch_bounds__(256) void k2b_wiht(const float* __restrict__ Wih,
                                                float* __restrict__ ws){
  int idx = blockIdx.x*256 + threadIdx.x;
  if (idx >= PRED*G3) return;
  int r = idx / PRED, i = idx % PRED;
  ws[WS_WIHT + i*G3 + r] = Wih[r*IN_DIM + i];
}

// ---------------- K3: encoder GRU (unchanged from passing r5) ----------------
__global__ __launch_bounds__(384) void k3_enc(const float* __restrict__ Whh,
                                              const float* __restrict__ bhh,
                                              float* __restrict__ ws){
  __shared__ __align__(16) float h[HID];
  __shared__ float grz[256];
  __shared__ float hnv[HID];
  int r = threadIdx.x;
  float4 w[32];
  const float4* wr = (const float4*)(Whh + r*HID);
  #pragma unroll
  for(int i=0;i<32;i++) w[i] = wr[i];
  float bh = (r>=256)? bhh[r] : 0.0f;
  if (r < HID) h[r] = 0.0f;
  __syncthreads();
  const float* encgi = ws + WS_ENCGI;
  for(int t=0;t<CNTX;t++){
    float acc = 0.f;
    #pragma unroll
    for(int i=0;i<32;i++){
      float4 hv = *(const float4*)&h[4*i];
      float4 ww = w[i];
      acc = fmaf(ww.x,hv.x, fmaf(ww.y,hv.y, fmaf(ww.z,hv.z, fmaf(ww.w,hv.w, acc))));
    }
    if (r < 256) grz[r] = encgi[t*G3+r] + acc;
    else         hnv[r-256] = acc + bh;
    __syncthreads();
    if (r < HID){
      float rr = 1.0f/(1.0f+expf(-grz[r]));
      float zz = 1.0f/(1.0f+expf(-grz[128+r]));
      float inv = encgi[t*G3+256+r];
      float nn = tanhf(inv + rr*hnv[r]);
      h[r] = (1.0f-zz)*nn + zz*h[r];
    }
    __syncthreads();
  }
  if (r < HID) ws[WS_HLAST + r] = h[r];
}

// ---------------- K4: decoder, 256 blocks x 512 thr, 32 samples/block ----------------
// BK=32 k-chunks, double-buffered transposed W tile (padded rows: G3P=385),
// 1 barrier per chunk, staging loads issued a chunk ahead (latency hidden).
#define SPB 32
#define THR 512
#define HROW 132
#define BK 32
#define G3P 385   // padded row length: bank = (ku + rr) % 32 -> <=2-way everywhere

__global__ __launch_bounds__(512) void k4_dec(const float* __restrict__ Whh,
                                              const float* __restrict__ bhh,
                                              const float* __restrict__ Wproj,
                                              const float* __restrict__ bproj,
                                              const float* __restrict__ ws,
                                              float* __restrict__ out){
  __shared__ __align__(16) float wT[2][BK*G3P];    // 2 x 48.1 KB
  __shared__ __align__(16) float h[SPB][HROW];     // 16.9 KB
  __shared__ float shist[SPB][PRED];
  __shared__ float parr[SPB][4];
  __shared__ float wp[HID*3];
  __shared__ float bp[3];
  __shared__ uint32_t skeys[PRED*4];

  int t = threadIdx.x;
  int b = blockIdx.x;
  int lane = t & 63;
  int sp = t >> 6;              // wave id = sample group (4 samples)
  int j0 = lane, j1 = lane + 64;
  int s_base = sp*4;

  float sc = ws[WS_SC];
  const float* gish = ws + WS_GISH;
  const float* wihT = ws + WS_WIHT;

  for(int idx=t; idx<HID*3; idx+=THR) wp[idx] = Wproj[idx];
  if (t < 3) bp[t] = bproj[t];
  if (t < PRED*4) skeys[t] = reinterpret_cast<const uint32_t*>(ws + WS_KEYS)[t];
  {
    float h0 = ws[WS_HLAST + j0], h1 = ws[WS_HLAST + j1];
    #pragma unroll
    for(int ss=0;ss<4;ss++){ h[s_base+ss][j0] = h0; h[s_base+ss][j1] = h1; }
  }
  float bhn0 = bhh[256+j0], bhn1 = bhh[256+j1];

  // prologue: stage chunk 0 into wT[0]
  #pragma unroll
  for(int i=0;i<6;i++){
    int f4 = i*THR + t;             // 0..3071 float4 slots (384 rows x 8 quads)
    int rr = f4 >> 3, q = f4 & 7;
    float4 g = *(const float4*)&Whh[rr*HID + q*4];
    wT[0][(q*4+0)*G3P + rr] = g.x;
    wT[0][(q*4+1)*G3P + rr] = g.y;
    wT[0][(q*4+2)*G3P + rr] = g.z;
    wT[0][(q*4+3)*G3P + rr] = g.w;
  }
  __syncthreads();
  int p = 0;

  #pragma unroll 1
  for(int k=0;k<PRED;k++){
    float aR[4][2], aZ[4][2], aHN[4][2], aIN[4][2];
    float g_r0 = gish[k*G3 + j0],      g_r1 = gish[k*G3 + j1];
    float g_z0 = gish[k*G3 + 128+j0],  g_z1 = gish[k*G3 + 128+j1];
    float g_n0 = gish[k*G3 + 256+j0],  g_n1 = gish[k*G3 + 256+j1];
    #pragma unroll
    for(int ss=0;ss<4;ss++){
      aR[ss][0]=g_r0;  aR[ss][1]=g_r1;
      aZ[ss][0]=g_z0;  aZ[ss][1]=g_z1;
      aIN[ss][0]=g_n0; aIN[ss][1]=g_n1;
      aHN[ss][0]=bhn0; aHN[ss][1]=bhn1;
    }
    // recent generated-sample lag contributions (i < k)
    #pragma unroll 1
    for(int i=0;i<k;i++){
      const float* wrow = wihT + i*G3;
      float w_r0 = wrow[j0],     w_r1 = wrow[j1];
      float w_z0 = wrow[128+j0], w_z1 = wrow[128+j1];
      float w_n0 = wrow[256+j0], w_n1 = wrow[256+j1];
      #pragma unroll
      for(int ss=0;ss<4;ss++){
        float sh = shist[s_base+ss][k-1-i];
        aR[ss][0]  = fmaf(w_r0, sh, aR[ss][0]);  aR[ss][1]  = fmaf(w_r1, sh, aR[ss][1]);
        aZ[ss][0]  = fmaf(w_z0, sh, aZ[ss][0]);  aZ[ss][1]  = fmaf(w_z1, sh, aZ[ss][1]);
        aIN[ss][0] = fmaf(w_n0, sh, aIN[ss][0]); aIN[ss][1] = fmaf(w_n1, sh, aIN[ss][1]);
      }
    }
    // main h-matvec: 4 chunks of BK=32, double-buffered, 1 barrier each.
    // k-order remains strictly sequential 0..127 (bit-identical accumulation).
    #pragma unroll 1
    for(int c=0;c<4;c++){
      // issue loads for next chunk (for c==3: chunk 0, used by the next step)
      int cn = (c+1)&3;
      float4 stg[6];
      int srr[6], sq[6];
      #pragma unroll
      for(int i=0;i<6;i++){
        int f4 = i*THR + t;
        srr[i] = f4 >> 3; sq[i] = f4 & 7;
        stg[i] = *(const float4*)&Whh[srr[i]*HID + cn*BK + sq[i]*4];
      }
      // compute chunk c from wT[p]
      const float* wcur = wT[p];
      #pragma unroll
      for(int kq=0;kq<8;kq++){
        float hx[4], hy[4], hz[4], hw[4];
        #pragma unroll
        for(int ss=0;ss<4;ss++){
          float4 hv = *(const float4*)&h[s_base+ss][c*BK + kq*4];
          hx[ss]=hv.x; hy[ss]=hv.y; hz[ss]=hv.z; hw[ss]=hv.w;
        }
        #pragma unroll
        for(int u=0;u<4;u++){
          const float* wc = wcur + (kq*4+u)*G3P;
          float wr0 = wc[j0],     wr1 = wc[j0+64];
          float wz0 = wc[j0+128], wz1 = wc[j0+192];
          float wn0 = wc[j0+256], wn1 = wc[j0+320];
          #pragma unroll
          for(int ss=0;ss<4;ss++){
            float hc = (u==0)?hx[ss]:(u==1)?hy[ss]:(u==2)?hz[ss]:hw[ss];
            aR[ss][0]  = fmaf(wr0, hc, aR[ss][0]);  aR[ss][1]  = fmaf(wr1, hc, aR[ss][1]);
            aZ[ss][0]  = fmaf(wz0, hc, aZ[ss][0]);  aZ[ss][1]  = fmaf(wz1, hc, aZ[ss][1]);
            aHN[ss][0] = fmaf(wn0, hc, aHN[ss][0]); aHN[ss][1] = fmaf(wn1, hc, aHN[ss][1]);
          }
        }
      }
      // write staged chunk into the other buffer
      float* wnx = wT[p^1];
      #pragma unroll
      for(int i=0;i<6;i++){
        wnx[(sq[i]*4+0)*G3P + srr[i]] = stg[i].x;
        wnx[(sq[i]*4+1)*G3P + srr[i]] = stg[i].y;
        wnx[(sq[i]*4+2)*G3P + srr[i]] = stg[i].z;
        wnx[(sq[i]*4+3)*G3P + srr[i]] = stg[i].w;
      }
      __syncthreads();
      p ^= 1;
    }
    // gates + h update (identical math/order to r5)
    #pragma unroll
    for(int ss=0;ss<4;ss++){
      int s = s_base+ss;
      {
        float rr = 1.0f/(1.0f+expf(-aR[ss][0]));
        float zz = 1.0f/(1.0f+expf(-aZ[ss][0]));
        float nn = tanhf(aIN[ss][0] + rr*aHN[ss][0]);
        h[s][j0] = (1.0f-zz)*nn + zz*h[s][j0];
      }
      {
        float rr = 1.0f/(1.0f+expf(-aR[ss][1]));
        float zz = 1.0f/(1.0f+expf(-aZ[ss][1]));
        float nn = tanhf(aIN[ss][1] + rr*aHN[ss][1]);
        h[s][j1] = (1.0f-zz)*nn + zz*h[s][j1];
      }
    }
    __syncthreads();
    // projection: 96 threads (identical order to r5)
    if (t < SPB*3){
      int s = t/3, c2 = t%3;
      float acc = bp[c2];
      for(int l=0;l<HID;l++) acc = fmaf(h[s][l], wp[l*3+c2], acc);
      parr[s][c2] = acc;
    }
    __syncthreads();
    // sampling: 32 threads (identical to r5)
    if (t < SPB){
      int s = t, gs = b*SPB + s;
      float p0 = parr[s][0], loc = parr[s][1], p2 = parr[s][2];
      float df = 2.0f + softplus_f(p0);
      float half_df = df*0.5f;
      float sigma = softplus_f(p2);
      uint32_t kn0 = skeys[k*4+0], kn1 = skeys[k*4+1];
      uint32_t kg0 = skeys[k*4+2], kg1 = skeys[k*4+3];
      uint32_t bnb = tf_bits_at(kn0, kn1, (uint32_t)gs);
      const float lo = -0.99999994f;
      float un = fmaxf(lo, bits_to_f01(bnb)*2.0f + lo);
      float nval = 1.41421356f * erfinv32(un);
      uint32_t gk0, gk1;
      threefry(kg0, kg1, 0u, (uint32_t)gs, gk0, gk1);
      float g = gamma_sample(gk0, gk1, half_df);
      float tval = nval * sqrtf(half_df / g);
      float samp = (loc + sigma*tval)*sc;
      out[gs*PRED + k] = samp;
      shist[s][k] = samp / sc;
    }
    __syncthreads();
  }
}

extern "C" void kernel_launch(void* const* d_in, const int* in_sizes, int n_in,
                              void* d_out, int out_size, void* d_ws, size_t ws_size,
                              hipStream_t stream){
  const float* x     = (const float*)d_in[0];
  const float* xmark = (const float*)d_in[1];
  const float* ymark = (const float*)d_in[2];
  const float* Wemb  = (const float*)d_in[3];
  const float* bemb  = (const float*)d_in[4];
  const float* Wih   = (const float*)d_in[5];
  const float* Whh   = (const float*)d_in[6];
  const float* bih   = (const float*)d_in[7];
  const float* bhh   = (const float*)d_in[8];
  const float* Wproj = (const float*)d_in[9];
  const float* bproj = (const float*)d_in[10];
  float* ws  = (float*)d_ws;
  float* out = (float*)d_out;

  hipLaunchKernelGGL(k1_prep, dim3(1), dim3(256), 0, stream, x, xmark, ymark, Wemb, bemb, ws);
  hipLaunchKernelGGL(k2_gi, dim3(288), dim3(256), 0, stream, Wih, bih, bhh, ws);
  hipLaunchKernelGGL(k2b_wiht, dim3((PRED*G3+255)/256), dim3(256), 0, stream, Wih, ws);
  hipLaunchKernelGGL(k3_enc, dim3(1), dim3(384), 0, stream, Whh, bhh, ws);
  hipLaunchKernelGGL(k4_dec, dim3(NSAMP/SPB), dim3(THR), 0, stream, Whh, bhh, Wproj, bproj, ws, out);
}